// Round 4
// baseline (277.133 us; speedup 1.0000x reference)
//
#include <hip/hip_runtime.h>
#include <hip/hip_bf16.h>
#include <cstdint>
#include <cstddef>

// Problem constants
#define Bsz 4
#define Tsz 8192
#define Dsz 512
#define Hn 8
#define BSn 16
#define NBn 512     // T/BS blocks (attention sequence length)
#define DHn 64      // head dim
#define NQKV 1536   // 3*D
#define MROWS 32768 // B*T

// softmax scale folded with log2(e), applied to Q at gemm epilogue
#define SCL 0.06375870136f
// fixed softmax max (exp2 domain); constant offset cancels in p/sum(p)
#define ATT_M 8.0f

typedef __attribute__((ext_vector_type(8))) short short8;
typedef __attribute__((ext_vector_type(4))) float float4f;

__device__ __forceinline__ uint16_t f2b(float f) {
  union { float f; uint32_t u; } v; v.f = f;
  uint32_t u = v.u;
  return (uint16_t)((u + 0x7fffu + ((u >> 16) & 1u)) >> 16);  // RNE
}

// pack two f32 -> (bf16(b)<<16)|bf16(a), round-half-up (bias ~2^-17, negligible)
__device__ __forceinline__ uint32_t pk2(float a, float b) {
  union { float f; uint32_t u; } x, y; x.f = a; y.f = b;
  return __builtin_amdgcn_perm(y.u + 0x8000u, x.u + 0x8000u, 0x07060302u);
}

// truncating variant (softmax P only; l sums the same raw p so it stays consistent)
__device__ __forceinline__ uint32_t pk2t(float a, float b) {
  union { float f; uint32_t u; } x, y; x.f = a; y.f = b;
  return __builtin_amdgcn_perm(y.u, x.u, 0x07060302u);
}

// async 16B global -> LDS (wave-uniform LDS base + lane*16)
__device__ __forceinline__ void gl_lds16(const void* g, void* l) {
  __builtin_amdgcn_global_load_lds(
      (const __attribute__((address_space(1))) unsigned int*)g,
      (__attribute__((address_space(3))) unsigned int*)l, 16, 0, 0);
}

// ---------------- fused convert kernel (x and Wq/Wk/Wv -> bf16) ----------------
#define XBLK (MROWS * Dsz / 1024)   // 16384 blocks for x
__global__ void cvt_kernel(const float* __restrict__ x, const float* __restrict__ Wq,
                           const float* __restrict__ Wk, const float* __restrict__ Wv,
                           uint16_t* __restrict__ xb, uint16_t* __restrict__ wc) {
  int bid = blockIdx.x;
  if (bid < XBLK) {
    int i = (bid * 256 + threadIdx.x) * 4;
    float4 v = *(const float4*)(x + i);
    uint64_t o = (uint64_t)pk2(v.x, v.y) | ((uint64_t)pk2(v.z, v.w) << 32);
    *(uint64_t*)(xb + i) = o;
  } else {
    int i = ((bid - XBLK) * 256 + threadIdx.x) * 4;  // i < 1536*512
    int row = i >> 9;
    int col = i & 511;
    const float* src = (row < 512) ? Wq : ((row < 1024) ? Wk : Wv);
    float4 v = *(const float4*)(src + (size_t)(row & 511) * 512 + col);
    uint64_t o = (uint64_t)pk2(v.x, v.y) | ((uint64_t)pk2(v.z, v.w) << 32);
    *(uint64_t*)(wc + i) = o;
  }
}

// ---------------- QKV projection GEMM ----------------
// Y[M=32768, N=1536] = Xb[M,512] * Wc[N,512]^T + bias.  BK=64, XOR-swizzled LDS,
// XCD-aware block swizzle.  MFMA operand-SWAPPED: acc rows = feature dim, so the
// epilogue packs 4 contiguous dh per lane -> b64 stores (16 instead of 64 b16).
#define BM 128
#define BN 128
#define BK 64

__global__ __launch_bounds__(256) void gemm_qkv(
    const uint16_t* __restrict__ Xb, const uint16_t* __restrict__ Wc,
    const float* __restrict__ bq, const float* __restrict__ bkp,
    const float* __restrict__ bv, uint16_t* __restrict__ Qp,
    uint16_t* __restrict__ Kp, uint16_t* __restrict__ Vtmp) {
  __shared__ uint16_t As[BM * BK];  // 16KB, row=64 elems=8 chunks, pos = c ^ (row&7)
  __shared__ uint16_t Bs[BN * BK];
  const int tid = threadIdx.x;
  const int wave = tid >> 6, lane = tid & 63;
  const int lrow = lane & 15, quad = lane >> 4;

  // XCD swizzle: keep one m-tile's 12 n-blocks on one XCD.
  int g = blockIdx.x;
  int xcd = g & 7, ii = g >> 3;        // ii in [0,384)
  int mt = xcd * 32 + ii / 12;
  int nt = ii - (ii / 12) * 12;
  const int m0 = mt * BM;
  const int n0 = nt * BN;
  const int wm = (wave >> 1) * 64, wn = (wave & 1) * 64;

  float4f acc[4][4] = {};   // [j: n-subtile][i: m-subtile], rows = n-dim (dh)

  for (int k0 = 0; k0 < Dsz; k0 += BK) {
    __syncthreads();
#pragma unroll
    for (int p = 0; p < 4; ++p) {
      int cbase = p * 256 + wave * 64;   // wave-uniform chunk base
      int c = cbase + lane;
      int row = c >> 3, pos = c & 7;
      int kc = (pos ^ (row & 7)) * 8;    // swizzle on the GLOBAL side (free)
      gl_lds16(Xb + (size_t)(m0 + row) * Dsz + k0 + kc, As + cbase * 8);
      gl_lds16(Wc + (size_t)(n0 + row) * Dsz + k0 + kc, Bs + cbase * 8);
    }
    __syncthreads();

#pragma unroll
    for (int h = 0; h < 2; ++h) {
      short8 af[4], bf[4];
#pragma unroll
      for (int i = 0; i < 4; ++i) {
        int rowA = wm + i * 16 + lrow;
        af[i] = *(const short8*)(As + rowA * BK + (((h * 4 + quad) ^ (rowA & 7)) * 8));
        int rowB = wn + i * 16 + lrow;
        bf[i] = *(const short8*)(Bs + rowB * BK + (((h * 4 + quad) ^ (rowB & 7)) * 8));
      }
#pragma unroll
      for (int j = 0; j < 4; ++j)
#pragma unroll
        for (int i = 0; i < 4; ++i)
          acc[j][i] = __builtin_amdgcn_mfma_f32_16x16x32_bf16(bf[j], af[i], acc[j][i], 0, 0, 0);
    }
  }

  // epilogue: lane holds nl = (n0&511)+wn + j*16 + quad*4 + r  (r contiguous!),
  // token = m0 + wm + i*16 + lrow  -> s = lrow, nb = nbbase + i
  const int region = n0 >> 9;  // 0=Q, 1=K, 2=V
  const float* bias = (region == 0) ? bq : ((region == 1) ? bkp : bv);
  const float mult = (region == 0) ? SCL : 1.0f;
  const int bb = m0 >> 13;
  const int nbbase = ((m0 & 8191) >> 4) + (wm >> 4);
  const int nv0 = (n0 & 511) + wn;   // multiple of 64

  if (region < 2) {
    uint16_t* dst = (region == 0) ? Qp : Kp;
    const int hh = nv0 >> 6;
    uint16_t* plane = dst + ((((size_t)bb * 16 + lrow) * 8 + hh) << 15);
#pragma unroll
    for (int j = 0; j < 4; ++j) {
      int dh0 = j * 16 + quad * 4;
      float4 bv4 = *(const float4*)(bias + nv0 + dh0);
#pragma unroll
      for (int i = 0; i < 4; ++i) {
        float4f a = acc[j][i];
        uint2 st = make_uint2(pk2((a[0] + bv4.x) * mult, (a[1] + bv4.y) * mult),
                              pk2((a[2] + bv4.z) * mult, (a[3] + bv4.w) * mult));
        *(uint2*)(plane + (size_t)(nbbase + i) * 64 + dh0) = st;
      }
    }
  } else {
#pragma unroll
    for (int j = 0; j < 4; ++j) {
      int c0 = nv0 + j * 16 + quad * 4;
      float4 bv4 = *(const float4*)(bias + c0);
#pragma unroll
      for (int i = 0; i < 4; ++i) {
        int token = m0 + wm + i * 16 + lrow;
        float4f a = acc[j][i];
        uint2 st = make_uint2(pk2(a[0] + bv4.x, a[1] + bv4.y),
                              pk2(a[2] + bv4.z, a[3] + bv4.w));
        *(uint2*)(Vtmp + (size_t)token * 512 + c0) = st;
      }
    }
  }
}

// ---------------- V transpose: Vtmp[32768][512] -> Vt[(b,s,h)][dh=64][nb=512] ----------------
__global__ __launch_bounds__(256) void vtrans(const uint16_t* __restrict__ Vtmp,
                                              uint16_t* __restrict__ Vt) {
  __shared__ uint16_t tile[64 * 64];  // [nb_local][dh], 16B chunks XOR-swizzled by row
  int bx = blockIdx.x;
  const int nt = bx & 7; bx >>= 3;
  const int h = bx & 7; bx >>= 3;
  const int s = bx & 15;
  const int b = bx >> 4;
  const int tid = threadIdx.x;

  {  // read 64 tokens x 64 dh; thread: row i, two 16B chunks
    int i = tid >> 2;
    int token = b * Tsz + (nt * 64 + i) * BSn + s;
    const uint16_t* src = Vtmp + (size_t)token * 512 + h * 64;
#pragma unroll
    for (int hh = 0; hh < 2; ++hh) {
      int ch = (tid & 3) * 2 + hh;
      short8 v = *(const short8*)(src + ch * 8);
      int pc = ch ^ (i & 7);
      *(short8*)(tile + i * 64 + pc * 8) = v;
    }
  }
  __syncthreads();
  {  // write: wave-major dh for conflict-free column gather
    int dh = tid & 63, seg = tid >> 6;
    short8 v1, v2;
#pragma unroll
    for (int k = 0; k < 8; ++k) {
      int nb_l = seg * 16 + k;
      v1[k] = (short)tile[nb_l * 64 + (((dh >> 3) ^ (nb_l & 7)) * 8) + (dh & 7)];
    }
#pragma unroll
    for (int k = 0; k < 8; ++k) {
      int nb_l = seg * 16 + 8 + k;
      v2[k] = (short)tile[nb_l * 64 + (((dh >> 3) ^ (nb_l & 7)) * 8) + (dh & 7)];
    }
    size_t obase = ((((size_t)b * 16 + s) * 8 + h) * 64 + dh) * 512 + nt * 64 + seg * 16;
    *(short8*)(Vt + obase) = v1;
    *(short8*)(Vt + obase + 8) = v2;
  }
}

// ---------------- fused block attention, S^T orientation, fixed-max softmax ----------------
__global__ __launch_bounds__(256, 3) void attn_kernel(
    const uint16_t* __restrict__ Qp, const uint16_t* __restrict__ Kp,
    const uint16_t* __restrict__ Vt, float* __restrict__ out) {
  __shared__ uint16_t Ks[32 * 64];        // K tile, rows 128B, chunk pos = c ^ (r&7)
  __shared__ uint16_t Vs[64 * 32];        // V^T tile, rows 64B, pos = c ^ ((r>>1)&3)
  __shared__ uint16_t Ps[4][4][16 * 32];  // [wave][qs] P [q][kv], pos = c ^ ((q>>1)&3)

  int bx = blockIdx.x;
  const int qh = bx & 1; bx >>= 1;
  const int h = bx & 7; bx >>= 3;
  const int s = bx & 15;
  const int b = bx >> 4;

  const int tid = threadIdx.x;
  const int w = tid >> 6, lane = tid & 63;
  const int lrow = lane & 15, quad = lane >> 4;

  const size_t sh = (((size_t)b * 16 + s) * 8 + h);
  const uint16_t* Qb = Qp + (sh << 15);   // [512 nb][64 dh]
  const uint16_t* Kb = Kp + (sh << 15);   // [512 nb][64 dh]
  const uint16_t* Vb = Vt + (sh << 15);   // [64 dh][512 nb]

  // Q B-fragments (persistent): 4 q-subtiles x 2 dh-chunks
  short8 qB[4][2];
  const int q0 = qh * 256 + w * 64;
#pragma unroll
  for (int qs = 0; qs < 4; ++qs) {
    const uint16_t* qp = Qb + (size_t)(q0 + qs * 16 + lrow) * 64;
    qB[qs][0] = *(const short8*)(qp + quad * 8);
    qB[qs][1] = *(const short8*)(qp + 32 + quad * 8);
  }

  float4f O[4][4] = {};                 // [dh tile][q subtile], C-layout (col=q)
  float l_acc[4] = {0.f, 0.f, 0.f, 0.f};

  const int kr = w * 8 + (lane >> 3);
  const int kcs = (lane & 7) ^ (kr & 7);
  const int vr = w * 16 + (lane >> 2);
  const int vcs = (lane & 3) ^ ((vr >> 1) & 3);

  const int sw = (lrow >> 1) & 3;
  const float4f negm = {-ATT_M, -ATT_M, -ATT_M, -ATT_M};

  for (int kv0 = 0; kv0 < NBn; kv0 += 32) {
    __syncthreads();
    gl_lds16(Kb + (size_t)(kv0 + kr) * 64 + kcs * 8, Ks + w * 512);
    gl_lds16(Vb + (size_t)vr * 512 + kv0 + vcs * 8, Vs + w * 512);
    __syncthreads();

    // ---- S-phase: K A-fragments, scores, exp2, pack into Ps ----
    {
      short8 kA[2][2];
#pragma unroll
      for (int kt = 0; kt < 2; ++kt) {
        int row = kt * 16 + lrow;
#pragma unroll
        for (int kc = 0; kc < 2; ++kc) {
          int cc = (kc * 4 + quad) ^ (row & 7);
          kA[kt][kc] = *(const short8*)(Ks + row * 64 + cc * 8);
        }
      }
#pragma unroll
      for (int qs = 0; qs < 4; ++qs) {
        // C pre-loaded with -M: exp2 args come out of MFMA directly
        float4f c0 = negm, c1 = negm;
        c0 = __builtin_amdgcn_mfma_f32_16x16x32_bf16(kA[0][0], qB[qs][0], c0, 0, 0, 0);
        c0 = __builtin_amdgcn_mfma_f32_16x16x32_bf16(kA[0][1], qB[qs][1], c0, 0, 0, 0);
        c1 = __builtin_amdgcn_mfma_f32_16x16x32_bf16(kA[1][0], qB[qs][0], c1, 0, 0, 0);
        c1 = __builtin_amdgcn_mfma_f32_16x16x32_bf16(kA[1][1], qB[qs][1], c1, 0, 0, 0);

        float p00 = __builtin_amdgcn_exp2f(c0[0]);
        float p01 = __builtin_amdgcn_exp2f(c0[1]);
        float p02 = __builtin_amdgcn_exp2f(c0[2]);
        float p03 = __builtin_amdgcn_exp2f(c0[3]);
        float p10 = __builtin_amdgcn_exp2f(c1[0]);
        float p11 = __builtin_amdgcn_exp2f(c1[1]);
        float p12 = __builtin_amdgcn_exp2f(c1[2]);
        float p13 = __builtin_amdgcn_exp2f(c1[3]);
        l_acc[qs] += ((p00 + p01) + (p02 + p03)) + ((p10 + p11) + (p12 + p13));

        uint32_t d0 = pk2t(p00, p01), d1 = pk2t(p02, p03);
        uint32_t d2 = pk2t(p10, p11), d3 = pk2t(p12, p13);
        uint16_t* Psq = Ps[w][qs];
        int half = (quad & 1) * 4;
        *(uint2*)(Psq + lrow * 32 + (((quad >> 1)) ^ sw) * 8 + half) = make_uint2(d0, d1);
        *(uint2*)(Psq + lrow * 32 + ((2 + (quad >> 1)) ^ sw) * 8 + half) = make_uint2(d2, d3);
      }
    }

    // ---- PV-phase: V^T A-fragments, P B-fragments, accumulate O ----
    {
      short8 vA[4];
#pragma unroll
      for (int dt = 0; dt < 4; ++dt) {
        int row = dt * 16 + lrow;
        vA[dt] = *(const short8*)(Vs + row * 32 + (quad ^ ((row >> 1) & 3)) * 8);
      }
#pragma unroll
      for (int qs = 0; qs < 4; ++qs) {
        short8 pB = *(const short8*)(Ps[w][qs] + lrow * 32 + (quad ^ sw) * 8);
#pragma unroll
        for (int dt = 0; dt < 4; ++dt)
          O[dt][qs] = __builtin_amdgcn_mfma_f32_16x16x32_bf16(vA[dt], pB, O[dt][qs], 0, 0, 0);
      }
    }
  }

  // epilogue: reduce l across quads (kv partials), normalize, write fp32
#pragma unroll
  for (int qs = 0; qs < 4; ++qs) {
    float l = l_acc[qs];
    l += __shfl_xor(l, 16);
    l += __shfl_xor(l, 32);
    float inv = 1.0f / l;
    int qg = q0 + qs * 16 + lrow;   // nb index of this lane's q column
    float* op = out + ((size_t)b * Tsz + (size_t)qg * 16 + s) * Dsz + h * 64;
#pragma unroll
    for (int dt = 0; dt < 4; ++dt) {
      float4 vv;
      vv.x = O[dt][qs][0] * inv; vv.y = O[dt][qs][1] * inv;
      vv.z = O[dt][qs][2] * inv; vv.w = O[dt][qs][3] * inv;
      *(float4*)(op + dt * 16 + quad * 4) = vv;
    }
  }
}

// ---------------- launch ----------------
extern "C" void kernel_launch(void* const* d_in, const int* in_sizes, int n_in,
                              void* d_out, int out_size, void* d_ws, size_t ws_size,
                              hipStream_t stream) {
  const float* x  = (const float*)d_in[0];
  const float* Wq = (const float*)d_in[1];
  const float* bq = (const float*)d_in[2];
  const float* Wk = (const float*)d_in[3];
  const float* bk = (const float*)d_in[4];
  const float* Wv = (const float*)d_in[5];
  const float* bv = (const float*)d_in[6];
  float* out = (float*)d_out;

  // workspace: Qp | Kp | Vtmp | xb | wc ; Vt aliases xb (gemm done with xb first)
  uint16_t* Qp   = (uint16_t*)d_ws;
  uint16_t* Kp   = Qp + (size_t)16777216;
  uint16_t* Vtmp = Kp + (size_t)16777216;
  uint16_t* xb   = Vtmp + (size_t)16777216;
  uint16_t* wc   = xb + (size_t)16777216;
  uint16_t* Vt   = xb;  // alias

  hipLaunchKernelGGL(cvt_kernel, dim3(XBLK + NQKV * Dsz / 1024), dim3(256), 0, stream,
                     x, Wq, Wk, Wv, xb, wc);
  hipLaunchKernelGGL(gemm_qkv, dim3((MROWS / BM) * (NQKV / BN)), dim3(256), 0, stream,
                     xb, wc, bq, bk, bv, Qp, Kp, Vtmp);
  hipLaunchKernelGGL(vtrans, dim3(Bsz * BSn * Hn * 8), dim3(256), 0, stream, Vtmp, Vt);
  hipLaunchKernelGGL(attn_kernel, dim3(Bsz * BSn * Hn * 2), dim3(256), 0, stream,
                     Qp, Kp, Vt, out);
}

// Round 5
// 254.104 us; speedup vs baseline: 1.0906x; 1.0906x over previous
//
#include <hip/hip_runtime.h>
#include <hip/hip_bf16.h>
#include <cstdint>
#include <cstddef>

// Problem constants
#define Bsz 4
#define Tsz 8192
#define Dsz 512
#define Hn 8
#define BSn 16
#define NBn 512     // T/BS blocks (attention sequence length)
#define DHn 64      // head dim
#define NQKV 1536   // 3*D
#define MROWS 32768 // B*T

// softmax scale folded with log2(e), applied to Q at gemm epilogue
#define SCL 0.06375870136f
// fixed softmax max (exp2 domain); constant offset cancels in p/sum(p)
#define ATT_M 8.0f

typedef __attribute__((ext_vector_type(8))) short short8;
typedef __attribute__((ext_vector_type(4))) float float4f;

__device__ __forceinline__ uint16_t f2b(float f) {
  union { float f; uint32_t u; } v; v.f = f;
  uint32_t u = v.u;
  return (uint16_t)((u + 0x7fffu + ((u >> 16) & 1u)) >> 16);  // RNE
}

// pack two f32 -> (bf16(b)<<16)|bf16(a), round-half-up (bias ~2^-17, negligible)
__device__ __forceinline__ uint32_t pk2(float a, float b) {
  union { float f; uint32_t u; } x, y; x.f = a; y.f = b;
  return __builtin_amdgcn_perm(y.u + 0x8000u, x.u + 0x8000u, 0x07060302u);
}

// truncating variant (softmax P only; l sums the same raw p so it stays consistent)
__device__ __forceinline__ uint32_t pk2t(float a, float b) {
  union { float f; uint32_t u; } x, y; x.f = a; y.f = b;
  return __builtin_amdgcn_perm(y.u, x.u, 0x07060302u);
}

// async 16B global -> LDS (wave-uniform LDS base + lane*16)
__device__ __forceinline__ void gl_lds16(const void* g, void* l) {
  __builtin_amdgcn_global_load_lds(
      (const __attribute__((address_space(1))) unsigned int*)g,
      (__attribute__((address_space(3))) unsigned int*)l, 16, 0, 0);
}

// ---------------- fused convert kernel (x and Wq/Wk/Wv -> bf16) ----------------
#define XBLK (MROWS * Dsz / 1024)   // 16384 blocks for x
__global__ void cvt_kernel(const float* __restrict__ x, const float* __restrict__ Wq,
                           const float* __restrict__ Wk, const float* __restrict__ Wv,
                           uint16_t* __restrict__ xb, uint16_t* __restrict__ wc) {
  int bid = blockIdx.x;
  if (bid < XBLK) {
    int i = (bid * 256 + threadIdx.x) * 4;
    float4 v = *(const float4*)(x + i);
    uint64_t o = (uint64_t)pk2(v.x, v.y) | ((uint64_t)pk2(v.z, v.w) << 32);
    *(uint64_t*)(xb + i) = o;
  } else {
    int i = ((bid - XBLK) * 256 + threadIdx.x) * 4;  // i < 1536*512
    int row = i >> 9;
    int col = i & 511;
    const float* src = (row < 512) ? Wq : ((row < 1024) ? Wk : Wv);
    float4 v = *(const float4*)(src + (size_t)(row & 511) * 512 + col);
    uint64_t o = (uint64_t)pk2(v.x, v.y) | ((uint64_t)pk2(v.z, v.w) << 32);
    *(uint64_t*)(wc + i) = o;
  }
}

// ---------------- QKV projection GEMM ----------------
// Y[M=32768, N=1536] = Xb[M,512] * Wc[N,512]^T + bias.
// Tile 128x64 (BK=64): 6144 blocks = 24/CU so barrier/vmcnt drains overlap
// across ~6 co-resident blocks (LDS 24KB, launch_bounds(256,6)).
// Round-3 MFMA orientation (operand swap regressed in round 4).
#define BM 128
#define BN 64
#define BK 64

__global__ __launch_bounds__(256, 6) void gemm_qkv(
    const uint16_t* __restrict__ Xb, const uint16_t* __restrict__ Wc,
    const float* __restrict__ bq, const float* __restrict__ bkp,
    const float* __restrict__ bv, uint16_t* __restrict__ Qp,
    uint16_t* __restrict__ Kp, uint16_t* __restrict__ Vtmp) {
  __shared__ uint16_t As[BM * BK];  // 16KB, row=64 elems=8 chunks, pos = c ^ (row&7)
  __shared__ uint16_t Bs[BN * BK];  // 8KB
  const int tid = threadIdx.x;
  const int wave = tid >> 6, lane = tid & 63;
  const int lrow = lane & 15, quad = lane >> 4;

  // XCD swizzle: 24 n-blocks of one m-slice stay consecutive on one XCD.
  int g = blockIdx.x;
  int xcd = g & 7, ii = g >> 3;        // ii in [0,768)
  int mt = xcd * 32 + ii / 24;
  int nt = ii - (ii / 24) * 24;
  const int m0 = mt * BM;
  const int n0 = nt * BN;
  const int wm = (wave >> 1) * 64, wn = (wave & 1) * 32;  // wave tile 64m x 32n

  float4f acc[4][2] = {};   // [i: m-subtile][j: n-subtile]

  for (int k0 = 0; k0 < Dsz; k0 += BK) {
    __syncthreads();
#pragma unroll
    for (int p = 0; p < 4; ++p) {       // As: 1024 chunks
      int cbase = p * 256 + wave * 64;
      int c = cbase + lane;
      int row = c >> 3, pos = c & 7;
      int kc = (pos ^ (row & 7)) * 8;   // swizzle on the GLOBAL side (free)
      gl_lds16(Xb + (size_t)(m0 + row) * Dsz + k0 + kc, As + cbase * 8);
    }
#pragma unroll
    for (int p = 0; p < 2; ++p) {       // Bs: 512 chunks
      int cbase = p * 256 + wave * 64;
      int c = cbase + lane;
      int row = c >> 3, pos = c & 7;
      int kc = (pos ^ (row & 7)) * 8;
      gl_lds16(Wc + (size_t)(n0 + row) * Dsz + k0 + kc, Bs + cbase * 8);
    }
    __syncthreads();

#pragma unroll
    for (int h = 0; h < 2; ++h) {
      short8 af[4], bf[2];
#pragma unroll
      for (int i = 0; i < 4; ++i) {
        int rowA = wm + i * 16 + lrow;
        af[i] = *(const short8*)(As + rowA * BK + (((h * 4 + quad) ^ (rowA & 7)) * 8));
      }
#pragma unroll
      for (int j = 0; j < 2; ++j) {
        int rowB = wn + j * 16 + lrow;
        bf[j] = *(const short8*)(Bs + rowB * BK + (((h * 4 + quad) ^ (rowB & 7)) * 8));
      }
#pragma unroll
      for (int i = 0; i < 4; ++i)
#pragma unroll
        for (int j = 0; j < 2; ++j)
          acc[i][j] = __builtin_amdgcn_mfma_f32_16x16x32_bf16(af[i], bf[j], acc[i][j], 0, 0, 0);
    }
  }

  // epilogue (round-3 pattern): token s = quad*4+r, dh consecutive over lrow
  const int region = n0 >> 9;  // 0=Q, 1=K, 2=V (64 | 512 so no tile crosses)
  const float* bias = (region == 0) ? bq : ((region == 1) ? bkp : bv);
  const float mult = (region == 0) ? SCL : 1.0f;
  const int bb = m0 >> 13;
  const int nbbase = ((m0 & 8191) >> 4) + (wm >> 4);    // nb = nbbase + i
  const int nv0 = (n0 & 511) + wn;

  if (region < 2) {
    uint16_t* dst = (region == 0) ? Qp : Kp;
#pragma unroll
    for (int j = 0; j < 2; ++j) {
      int nl = nv0 + j * 16 + lrow;
      int hh = nl >> 6, dh = nl & 63;
      float bval = bias[nl];
      // addr = ((b*16+s)*8+h)*32768 + nb*64 + dh  (s = quad*4+r)
      size_t base = (size_t)bb * 4194304 + (size_t)hh * 32768 +
                    (size_t)nbbase * 64 + dh + (size_t)(quad * 4) * 262144;
#pragma unroll
      for (int i = 0; i < 4; ++i)
#pragma unroll
        for (int r = 0; r < 4; ++r)
          dst[base + (size_t)r * 262144 + (size_t)i * 64] =
              f2b((acc[i][j][r] + bval) * mult);
    }
  } else {
#pragma unroll
    for (int j = 0; j < 2; ++j) {
      int nl = nv0 + j * 16 + lrow;
      float bval = bias[nl];
#pragma unroll
      for (int i = 0; i < 4; ++i) {
        int tok = m0 + wm + i * 16 + quad * 4;
#pragma unroll
        for (int r = 0; r < 4; ++r)
          Vtmp[(size_t)(tok + r) * 512 + nl] = f2b(acc[i][j][r] + bval);
      }
    }
  }
}

// ---------------- V transpose: Vtmp[32768][512] -> Vt[(b,s,h)][dh=64][nb=512] ----------------
__global__ __launch_bounds__(256) void vtrans(const uint16_t* __restrict__ Vtmp,
                                              uint16_t* __restrict__ Vt) {
  __shared__ uint16_t tile[64 * 64];  // [nb_local][dh], 16B chunks XOR-swizzled by row
  int bx = blockIdx.x;
  const int nt = bx & 7; bx >>= 3;
  const int h = bx & 7; bx >>= 3;
  const int s = bx & 15;
  const int b = bx >> 4;
  const int tid = threadIdx.x;

  {  // read 64 tokens x 64 dh; thread: row i, two 16B chunks
    int i = tid >> 2;
    int token = b * Tsz + (nt * 64 + i) * BSn + s;
    const uint16_t* src = Vtmp + (size_t)token * 512 + h * 64;
#pragma unroll
    for (int hh = 0; hh < 2; ++hh) {
      int ch = (tid & 3) * 2 + hh;
      short8 v = *(const short8*)(src + ch * 8);
      int pc = ch ^ (i & 7);
      *(short8*)(tile + i * 64 + pc * 8) = v;
    }
  }
  __syncthreads();
  {  // write: wave-major dh for conflict-free column gather
    int dh = tid & 63, seg = tid >> 6;
    short8 v1, v2;
#pragma unroll
    for (int k = 0; k < 8; ++k) {
      int nb_l = seg * 16 + k;
      v1[k] = (short)tile[nb_l * 64 + (((dh >> 3) ^ (nb_l & 7)) * 8) + (dh & 7)];
    }
#pragma unroll
    for (int k = 0; k < 8; ++k) {
      int nb_l = seg * 16 + 8 + k;
      v2[k] = (short)tile[nb_l * 64 + (((dh >> 3) ^ (nb_l & 7)) * 8) + (dh & 7)];
    }
    size_t obase = ((((size_t)b * 16 + s) * 8 + h) * 64 + dh) * 512 + nt * 64 + seg * 16;
    *(short8*)(Vt + obase) = v1;
    *(short8*)(Vt + obase + 8) = v2;
  }
}

// ---------------- fused block attention, S^T orientation, fixed-max softmax ----------------
__global__ __launch_bounds__(256, 3) void attn_kernel(
    const uint16_t* __restrict__ Qp, const uint16_t* __restrict__ Kp,
    const uint16_t* __restrict__ Vt, float* __restrict__ out) {
  __shared__ uint16_t Ks[32 * 64];        // K tile, rows 128B, chunk pos = c ^ (r&7)
  __shared__ uint16_t Vs[64 * 32];        // V^T tile, rows 64B, pos = c ^ ((r>>1)&3)
  __shared__ uint16_t Ps[4][4][16 * 32];  // [wave][qs] P [q][kv], pos = c ^ ((q>>1)&3)

  int bx = blockIdx.x;
  const int qh = bx & 1; bx >>= 1;
  const int h = bx & 7; bx >>= 3;
  const int s = bx & 15;
  const int b = bx >> 4;

  const int tid = threadIdx.x;
  const int w = tid >> 6, lane = tid & 63;
  const int lrow = lane & 15, quad = lane >> 4;

  const size_t sh = (((size_t)b * 16 + s) * 8 + h);
  const uint16_t* Qb = Qp + (sh << 15);   // [512 nb][64 dh]
  const uint16_t* Kb = Kp + (sh << 15);   // [512 nb][64 dh]
  const uint16_t* Vb = Vt + (sh << 15);   // [64 dh][512 nb]

  // Q B-fragments (persistent): 4 q-subtiles x 2 dh-chunks
  short8 qB[4][2];
  const int q0 = qh * 256 + w * 64;
#pragma unroll
  for (int qs = 0; qs < 4; ++qs) {
    const uint16_t* qp = Qb + (size_t)(q0 + qs * 16 + lrow) * 64;
    qB[qs][0] = *(const short8*)(qp + quad * 8);
    qB[qs][1] = *(const short8*)(qp + 32 + quad * 8);
  }

  float4f O[4][4] = {};                 // [dh tile][q subtile], C-layout (col=q)
  float l_acc[4] = {0.f, 0.f, 0.f, 0.f};

  const int kr = w * 8 + (lane >> 3);
  const int kcs = (lane & 7) ^ (kr & 7);
  const int vr = w * 16 + (lane >> 2);
  const int vcs = (lane & 3) ^ ((vr >> 1) & 3);

  const int sw = (lrow >> 1) & 3;
  const float4f negm = {-ATT_M, -ATT_M, -ATT_M, -ATT_M};

  for (int kv0 = 0; kv0 < NBn; kv0 += 32) {
    __syncthreads();
    gl_lds16(Kb + (size_t)(kv0 + kr) * 64 + kcs * 8, Ks + w * 512);
    gl_lds16(Vb + (size_t)vr * 512 + kv0 + vcs * 8, Vs + w * 512);
    __syncthreads();

    // ---- S-phase: K A-fragments, scores, exp2, pack into Ps ----
    {
      short8 kA[2][2];
#pragma unroll
      for (int kt = 0; kt < 2; ++kt) {
        int row = kt * 16 + lrow;
#pragma unroll
        for (int kc = 0; kc < 2; ++kc) {
          int cc = (kc * 4 + quad) ^ (row & 7);
          kA[kt][kc] = *(const short8*)(Ks + row * 64 + cc * 8);
        }
      }
#pragma unroll
      for (int qs = 0; qs < 4; ++qs) {
        // C pre-loaded with -M: exp2 args come out of MFMA directly
        float4f c0 = negm, c1 = negm;
        c0 = __builtin_amdgcn_mfma_f32_16x16x32_bf16(kA[0][0], qB[qs][0], c0, 0, 0, 0);
        c0 = __builtin_amdgcn_mfma_f32_16x16x32_bf16(kA[0][1], qB[qs][1], c0, 0, 0, 0);
        c1 = __builtin_amdgcn_mfma_f32_16x16x32_bf16(kA[1][0], qB[qs][0], c1, 0, 0, 0);
        c1 = __builtin_amdgcn_mfma_f32_16x16x32_bf16(kA[1][1], qB[qs][1], c1, 0, 0, 0);

        float p00 = __builtin_amdgcn_exp2f(c0[0]);
        float p01 = __builtin_amdgcn_exp2f(c0[1]);
        float p02 = __builtin_amdgcn_exp2f(c0[2]);
        float p03 = __builtin_amdgcn_exp2f(c0[3]);
        float p10 = __builtin_amdgcn_exp2f(c1[0]);
        float p11 = __builtin_amdgcn_exp2f(c1[1]);
        float p12 = __builtin_amdgcn_exp2f(c1[2]);
        float p13 = __builtin_amdgcn_exp2f(c1[3]);
        l_acc[qs] += ((p00 + p01) + (p02 + p03)) + ((p10 + p11) + (p12 + p13));

        uint32_t d0 = pk2t(p00, p01), d1 = pk2t(p02, p03);
        uint32_t d2 = pk2t(p10, p11), d3 = pk2t(p12, p13);
        uint16_t* Psq = Ps[w][qs];
        int half = (quad & 1) * 4;
        *(uint2*)(Psq + lrow * 32 + (((quad >> 1)) ^ sw) * 8 + half) = make_uint2(d0, d1);
        *(uint2*)(Psq + lrow * 32 + ((2 + (quad >> 1)) ^ sw) * 8 + half) = make_uint2(d2, d3);
      }
    }

    // ---- PV-phase: V^T A-fragments, P B-fragments, accumulate O ----
    {
      short8 vA[4];
#pragma unroll
      for (int dt = 0; dt < 4; ++dt) {
        int row = dt * 16 + lrow;
        vA[dt] = *(const short8*)(Vs + row * 32 + (quad ^ ((row >> 1) & 3)) * 8);
      }
#pragma unroll
      for (int qs = 0; qs < 4; ++qs) {
        short8 pB = *(const short8*)(Ps[w][qs] + lrow * 32 + (quad ^ sw) * 8);
#pragma unroll
        for (int dt = 0; dt < 4; ++dt)
          O[dt][qs] = __builtin_amdgcn_mfma_f32_16x16x32_bf16(vA[dt], pB, O[dt][qs], 0, 0, 0);
      }
    }
  }

  // epilogue: reduce l across quads (kv partials), normalize, write fp32
#pragma unroll
  for (int qs = 0; qs < 4; ++qs) {
    float l = l_acc[qs];
    l += __shfl_xor(l, 16);
    l += __shfl_xor(l, 32);
    float inv = 1.0f / l;
    int qg = q0 + qs * 16 + lrow;   // nb index of this lane's q column
    float* op = out + ((size_t)b * Tsz + (size_t)qg * 16 + s) * Dsz + h * 64;
#pragma unroll
    for (int dt = 0; dt < 4; ++dt) {
      float4 vv;
      vv.x = O[dt][qs][0] * inv; vv.y = O[dt][qs][1] * inv;
      vv.z = O[dt][qs][2] * inv; vv.w = O[dt][qs][3] * inv;
      *(float4*)(op + dt * 16 + quad * 4) = vv;
    }
  }
}

// ---------------- launch ----------------
extern "C" void kernel_launch(void* const* d_in, const int* in_sizes, int n_in,
                              void* d_out, int out_size, void* d_ws, size_t ws_size,
                              hipStream_t stream) {
  const float* x  = (const float*)d_in[0];
  const float* Wq = (const float*)d_in[1];
  const float* bq = (const float*)d_in[2];
  const float* Wk = (const float*)d_in[3];
  const float* bk = (const float*)d_in[4];
  const float* Wv = (const float*)d_in[5];
  const float* bv = (const float*)d_in[6];
  float* out = (float*)d_out;

  // workspace: Qp | Kp | Vtmp | xb | wc ; Vt aliases xb (gemm done with xb first)
  uint16_t* Qp   = (uint16_t*)d_ws;
  uint16_t* Kp   = Qp + (size_t)16777216;
  uint16_t* Vtmp = Kp + (size_t)16777216;
  uint16_t* xb   = Vtmp + (size_t)16777216;
  uint16_t* wc   = xb + (size_t)16777216;
  uint16_t* Vt   = xb;  // alias

  hipLaunchKernelGGL(cvt_kernel, dim3(XBLK + NQKV * Dsz / 1024), dim3(256), 0, stream,
                     x, Wq, Wk, Wv, xb, wc);
  hipLaunchKernelGGL(gemm_qkv, dim3((MROWS / BM) * (NQKV / BN)), dim3(256), 0, stream,
                     xb, wc, bq, bk, bv, Qp, Kp, Vtmp);
  hipLaunchKernelGGL(vtrans, dim3(Bsz * BSn * Hn * 8), dim3(256), 0, stream, Vtmp, Vt);
  hipLaunchKernelGGL(attn_kernel, dim3(Bsz * BSn * Hn * 2), dim3(256), 0, stream,
                     Qp, Kp, Vt, out);
}